// Round 1
// baseline (434.824 us; speedup 1.0000x reference)
//
#include <hip/hip_runtime.h>
#include <math.h>

#define NN 8192
#define DD 128
#define INVT 10.0f
#define TI 64
#define TJ 64

// ---------------- kernel 1: per-row reciprocal L2 norm ----------------
__global__ __launch_bounds__(256) void norms_kernel(const float* __restrict__ x,
                                                    float* __restrict__ rnorm) {
    int row  = blockIdx.x * 4 + (threadIdx.x >> 6);
    int lane = threadIdx.x & 63;
    float2 v = ((const float2*)(x + (size_t)row * DD))[lane];
    float ss = v.x * v.x + v.y * v.y;
    #pragma unroll
    for (int off = 32; off > 0; off >>= 1) ss += __shfl_xor(ss, off);
    if (lane == 0) rnorm[row] = 1.0f / sqrtf(ss);
}

// stage a 64x128 fp32 tile into LDS, normalized, with XOR-swizzled 16B blocks
// (blk' = blk ^ ((row>>2)&7)) so the 4x4 outer-product reads are conflict-free.
__device__ __forceinline__ void stage_tile(const float* __restrict__ xbase,
                                           const float* __restrict__ rn,
                                           float (*dst)[DD], int t) {
    int row = t >> 2;        // 0..63
    int c4  = t & 3;         // 0..3
    int sw  = (row >> 2) & 7;
    float scale = rn[row];
    const float4* s   = (const float4*)(xbase + (size_t)row * DD);
    float4*      drow = (float4*)&dst[row][0];
    #pragma unroll
    for (int k = 0; k < 8; ++k) {
        int blk = k * 4 + c4;          // coalesced: 4 lanes cover 64B per row
        float4 v = s[blk];
        v.x *= scale; v.y *= scale; v.z *= scale; v.w *= scale;
        drow[blk ^ sw] = v;            // swizzled LDS slot
    }
}

// ---------------- kernel 2: main contrastive accumulation ----------------
// grid = 128 i-tiles x 2 j-halves = 256 blocks, 256 threads each.
// Each block computes a 64 x 4096 strip of the similarity matrix and writes
// per-row partial {Z, S_pos, pos_count} for its half.
__global__ __launch_bounds__(256) void cl_main(const float* __restrict__ x,
                                               const int* __restrict__ labels,
                                               const float* __restrict__ rnorm,
                                               float* __restrict__ Zp,
                                               float* __restrict__ Sp,
                                               float* __restrict__ Cp) {
    __shared__ float xi[TI][DD];     // 32 KB
    __shared__ float xj[TJ][DD];     // 32 KB
    __shared__ int   labJ[TJ];
    __shared__ float red[64][17];    // padded reduce buffer

    const int ibt   = (int)blockIdx.x >> 1;   // 0..127
    const int half  = (int)blockIdx.x & 1;
    const int ibase = ibt * TI;
    const int jstart = half * (NN / 2);
    const int t   = threadIdx.x;
    const int ti  = t & 15;          // i-group (4 rows each)
    const int tjg = t >> 4;          // j-group (4 cols each)
    const int swi = ti & 7;
    const int swj = tjg & 7;

    stage_tile(x + (size_t)ibase * DD, rnorm + ibase, xi, t);

    int labI[4];
    const int ig0 = ibase + ti * 4;
    #pragma unroll
    for (int r = 0; r < 4; ++r) labI[r] = labels[ig0 + r];

    float zA[4] = {0.f, 0.f, 0.f, 0.f};
    float sA[4] = {0.f, 0.f, 0.f, 0.f};
    float cA[4] = {0.f, 0.f, 0.f, 0.f};

    for (int jt = 0; jt < (NN / 2) / TJ; ++jt) {   // 64 tiles
        const int jbase = jstart + jt * TJ;
        __syncthreads();                            // protect xj reuse
        stage_tile(x + (size_t)jbase * DD, rnorm + jbase, xj, t);
        if (t < TJ) labJ[t] = labels[jbase + t];
        __syncthreads();

        float acc[4][4];
        #pragma unroll
        for (int r = 0; r < 4; ++r)
            #pragma unroll
            for (int c = 0; c < 4; ++c) acc[r][c] = 0.f;

        #pragma unroll 4
        for (int db = 0; db < 32; ++db) {          // 4 d's per iter
            float A[4][4], B[4][4];
            #pragma unroll
            for (int r = 0; r < 4; ++r) {
                float4 v = *(const float4*)&xi[ti * 4 + r][(db ^ swi) << 2];
                A[r][0] = v.x; A[r][1] = v.y; A[r][2] = v.z; A[r][3] = v.w;
            }
            #pragma unroll
            for (int c = 0; c < 4; ++c) {
                float4 v = *(const float4*)&xj[tjg * 4 + c][(db ^ swj) << 2];
                B[c][0] = v.x; B[c][1] = v.y; B[c][2] = v.z; B[c][3] = v.w;
            }
            #pragma unroll
            for (int r = 0; r < 4; ++r)
                #pragma unroll
                for (int c = 0; c < 4; ++c)
                    #pragma unroll
                    for (int kk = 0; kk < 4; ++kk)
                        acc[r][c] = fmaf(A[r][kk], B[c][kk], acc[r][c]);
        }

        // epilogue: scale, exp, masks, accumulate
        const int jg0 = jbase + tjg * 4;
        #pragma unroll
        for (int r = 0; r < 4; ++r) {
            const int ig = ig0 + r;
            const int li = labI[r];
            #pragma unroll
            for (int c = 0; c < 4; ++c) {
                const int jg = jg0 + c;
                float sc = acc[r][c] * INVT;
                float e  = __expf(sc);
                bool self = (ig == jg);
                bool pos  = (labJ[tjg * 4 + c] == li) && !self;
                zA[r] += self ? 0.f : e;
                sA[r] += pos ? sc : 0.f;
                cA[r] += pos ? 1.f : 0.f;
            }
        }
    }

    // cross-thread reduce (16 tjg partials per row), 3 quantities
    float* outZ = Zp + (size_t)half * NN + ibase;
    float* outS = Sp + (size_t)half * NN + ibase;
    float* outC = Cp + (size_t)half * NN + ibase;

    __syncthreads();
    #pragma unroll
    for (int r = 0; r < 4; ++r) red[ti * 4 + r][tjg] = zA[r];
    __syncthreads();
    if (t < 16) {
        #pragma unroll
        for (int r = 0; r < 4; ++r) {
            int row = t * 4 + r;
            float s = 0.f;
            #pragma unroll
            for (int k = 0; k < 16; ++k) s += red[row][k];
            outZ[row] = s;
        }
    }
    __syncthreads();
    #pragma unroll
    for (int r = 0; r < 4; ++r) red[ti * 4 + r][tjg] = sA[r];
    __syncthreads();
    if (t < 16) {
        #pragma unroll
        for (int r = 0; r < 4; ++r) {
            int row = t * 4 + r;
            float s = 0.f;
            #pragma unroll
            for (int k = 0; k < 16; ++k) s += red[row][k];
            outS[row] = s;
        }
    }
    __syncthreads();
    #pragma unroll
    for (int r = 0; r < 4; ++r) red[ti * 4 + r][tjg] = cA[r];
    __syncthreads();
    if (t < 16) {
        #pragma unroll
        for (int r = 0; r < 4; ++r) {
            int row = t * 4 + r;
            float s = 0.f;
            #pragma unroll
            for (int k = 0; k < 16; ++k) s += red[row][k];
            outC[row] = s;
        }
    }
}

// ---------------- kernel 3: finalize to scalar loss ----------------
__global__ __launch_bounds__(1024) void finalize_kernel(const float* __restrict__ Zp,
                                                        const float* __restrict__ Sp,
                                                        const float* __restrict__ Cp,
                                                        float* __restrict__ out) {
    float sum = 0.f, cnt = 0.f;
    for (int i = threadIdx.x; i < NN; i += 1024) {
        float Z = Zp[i] + Zp[NN + i];
        float S = Sp[i] + Sp[NN + i];
        float C = Cp[i] + Cp[NN + i];
        if (C > 0.f) { sum += S / C - logf(Z); cnt += 1.f; }
    }
    #pragma unroll
    for (int off = 32; off > 0; off >>= 1) {
        sum += __shfl_xor(sum, off);
        cnt += __shfl_xor(cnt, off);
    }
    __shared__ float rs[16], rc[16];
    int wave = threadIdx.x >> 6, lane = threadIdx.x & 63;
    if (lane == 0) { rs[wave] = sum; rc[wave] = cnt; }
    __syncthreads();
    if (threadIdx.x == 0) {
        float ts = 0.f, tc = 0.f;
        for (int w = 0; w < 16; ++w) { ts += rs[w]; tc += rc[w]; }
        out[0] = -ts / tc;
    }
}

extern "C" void kernel_launch(void* const* d_in, const int* in_sizes, int n_in,
                              void* d_out, int out_size, void* d_ws, size_t ws_size,
                              hipStream_t stream) {
    const float* x      = (const float*)d_in[0];
    const int*   labels = (const int*)d_in[1];
    float* out = (float*)d_out;
    char*  ws  = (char*)d_ws;

    float* rnorm = (float*)ws;                     // 32 KB
    float* Zp    = (float*)(ws + 32 * 1024);       // 64 KB (2 halves x 8192)
    float* Sp    = (float*)(ws + 96 * 1024);       // 64 KB
    float* Cp    = (float*)(ws + 160 * 1024);      // 64 KB

    norms_kernel<<<NN / 4, 256, 0, stream>>>(x, rnorm);
    cl_main<<<256, 256, 0, stream>>>(x, labels, rnorm, Zp, Sp, Cp);
    finalize_kernel<<<1, 1024, 0, stream>>>(Zp, Sp, Cp, out);
}

// Round 3
// 112.258 us; speedup vs baseline: 3.8734x; 3.8734x over previous
//
#include <hip/hip_runtime.h>
#include <math.h>

#define NN 8192
#define DD 128
#define JR 16            // j-ranges (grid second dim)
#define JW (NN / JR)     // 512 columns per j-range
#define KE 14.42695040888963f   // 10 * log2(e): exp(10*d) = exp2(d*KE)

typedef __attribute__((ext_vector_type(8))) short short8;
typedef __attribute__((ext_vector_type(4))) float f32x4;

__device__ __forceinline__ unsigned short f2bf(float f) {
    unsigned u = __builtin_bit_cast(unsigned, f);
    unsigned r = (u + 0x7FFFu + ((u >> 16) & 1u)) >> 16;
    return (unsigned short)r;
}
__device__ __forceinline__ float bf2f(unsigned short h) {
    unsigned u = ((unsigned)h) << 16;
    return __builtin_bit_cast(float, u);
}

// ------- kernel 1: normalize rows, cast to bf16, record selfdot -------
__global__ __launch_bounds__(256) void prep_kernel(const float* __restrict__ x,
                                                   unsigned short* __restrict__ xn,
                                                   float* __restrict__ sd) {
    int row  = (blockIdx.x << 2) + (threadIdx.x >> 6);
    int lane = threadIdx.x & 63;
    float2 v = ((const float2*)(x + (size_t)row * DD))[lane];
    float ss = v.x * v.x + v.y * v.y;
    #pragma unroll
    for (int off = 32; off; off >>= 1) ss += __shfl_xor(ss, off);
    float rn = rsqrtf(ss);
    unsigned short bx = f2bf(v.x * rn), by = f2bf(v.y * rn);
    ushort2 st; st.x = bx; st.y = by;
    ((ushort2*)(xn + (size_t)row * DD))[lane] = st;
    // selfdot of the bf16-rounded row (to cancel the diagonal later)
    float fx = bf2f(bx), fy = bf2f(by);
    float s2 = fx * fx + fy * fy;
    #pragma unroll
    for (int off = 32; off; off >>= 1) s2 += __shfl_xor(s2, off);
    if (lane == 0) sd[row] = s2;
}

// ------- kernel 2: MFMA similarity + online exp/mask accumulation -------
// Wave owns 64 rows x one 512-col j-range. No LDS; A,B frags direct from L1/L2.
__global__ __launch_bounds__(256, 2) void cl_main(const unsigned short* __restrict__ xn,
                                                  const int* __restrict__ labels,
                                                  float* __restrict__ Zp,
                                                  float* __restrict__ Sp) {
    const int tid  = threadIdx.x;
    const int wi   = tid >> 6;
    const int lane = tid & 63;
    const int l15  = lane & 15;
    const int lhi  = lane >> 4;
    const int b    = (int)blockIdx.x;
    const int jrange = b & 15;                  // 4 waves of a block share jrange
    const int strip  = ((b >> 4) << 2) | wi;    // 0..127
    const int row0   = strip << 6;

    // A fragments: lane holds A[row0 + mi*16 + l15][ks*32 + lhi*8 + 0..7]
    short8 a[4][4];
    #pragma unroll
    for (int mi = 0; mi < 4; ++mi)
        #pragma unroll
        for (int ks = 0; ks < 4; ++ks)
            a[mi][ks] = *(const short8*)(xn + (size_t)(row0 + mi * 16 + l15) * DD + ks * 32 + lhi * 8);

    // labels of the 16 rows this lane accumulates (C/D layout: row=(lane>>4)*4+r)
    int labI[4][4];
    #pragma unroll
    for (int mi = 0; mi < 4; ++mi)
        #pragma unroll
        for (int r = 0; r < 4; ++r)
            labI[mi][r] = labels[row0 + mi * 16 + lhi * 4 + r];

    float z[4][4], s[4][4];
    #pragma unroll
    for (int mi = 0; mi < 4; ++mi)
        #pragma unroll
        for (int r = 0; r < 4; ++r) { z[mi][r] = 0.f; s[mi][r] = 0.f; }

    const int j0r = jrange * JW;
    for (int t = 0; t < JW / 64; ++t) {        // 8 j-tiles of 64
        const int j0 = j0r + t * 64;
        int lj[4];
        #pragma unroll
        for (int ni = 0; ni < 4; ++ni) lj[ni] = labels[j0 + ni * 16 + l15];

        f32x4 acc[4][4];
        #pragma unroll
        for (int mi = 0; mi < 4; ++mi)
            #pragma unroll
            for (int ni = 0; ni < 4; ++ni) acc[mi][ni] = (f32x4){0.f, 0.f, 0.f, 0.f};

        #pragma unroll
        for (int ni = 0; ni < 4; ++ni) {
            short8 bf[4];
            #pragma unroll
            for (int ks = 0; ks < 4; ++ks)
                bf[ks] = *(const short8*)(xn + (size_t)(j0 + ni * 16 + l15) * DD + ks * 32 + lhi * 8);
            #pragma unroll
            for (int ks = 0; ks < 4; ++ks)
                #pragma unroll
                for (int mi = 0; mi < 4; ++mi)
                    acc[mi][ni] = __builtin_amdgcn_mfma_f32_16x16x32_bf16(a[mi][ks], bf[ks], acc[mi][ni], 0, 0, 0);
        }

        // epilogue: Z += exp(10*d) (self handled in finalize); S += d where labels match
        #pragma unroll
        for (int mi = 0; mi < 4; ++mi)
            #pragma unroll
            for (int ni = 0; ni < 4; ++ni)
                #pragma unroll
                for (int r = 0; r < 4; ++r) {
                    float d = acc[mi][ni][r];
                    z[mi][r] += __builtin_amdgcn_exp2f(d * KE);
                    s[mi][r] += (lj[ni] == labI[mi][r]) ? d : 0.f;
                }
    }

    // reduce across the 16 lanes (columns) sharing each row
    #pragma unroll
    for (int mi = 0; mi < 4; ++mi)
        #pragma unroll
        for (int r = 0; r < 4; ++r) {
            float zz = z[mi][r], ss = s[mi][r];
            #pragma unroll
            for (int off = 1; off < 16; off <<= 1) {
                zz += __shfl_xor(zz, off);
                ss += __shfl_xor(ss, off);
            }
            if (l15 == 0) {
                int row = row0 + mi * 16 + lhi * 4 + r;
                Zp[jrange * NN + row] = zz;
                Sp[jrange * NN + row] = ss;
            }
        }
}

// ------- kernel 3: per-row finalize + per-block partial loss -------
__global__ __launch_bounds__(256) void fin1(const float* __restrict__ Zp,
                                            const float* __restrict__ Sp,
                                            const float* __restrict__ sd,
                                            const int* __restrict__ labels,
                                            float* __restrict__ psum,
                                            float* __restrict__ pcnt) {
    __shared__ int cnt[33];
    __shared__ float rs[4], rc[4];
    int t = threadIdx.x;
    if (t < 33) cnt[t] = 0;
    __syncthreads();
    for (int i = t; i < NN; i += 256) atomicAdd(&cnt[labels[i]], 1);
    __syncthreads();

    int row = blockIdx.x * 256 + t;
    float Z = 0.f, S = 0.f;
    #pragma unroll
    for (int jr = 0; jr < JR; ++jr) {
        Z += Zp[jr * NN + row];
        S += Sp[jr * NN + row];
    }
    float sv = sd[row];
    Z -= __builtin_amdgcn_exp2f(sv * KE);   // remove self from denominator
    S -= sv;                                // remove self from positive-sum
    int C = cnt[labels[row]] - 1;
    float pr = 0.f, vl = 0.f;
    if (C > 0) { pr = 10.f * S / (float)C - logf(Z); vl = 1.f; }
    #pragma unroll
    for (int off = 32; off; off >>= 1) { pr += __shfl_xor(pr, off); vl += __shfl_xor(vl, off); }
    int wv = t >> 6, ln = t & 63;
    if (ln == 0) { rs[wv] = pr; rc[wv] = vl; }
    __syncthreads();
    if (t == 0) {
        psum[blockIdx.x] = rs[0] + rs[1] + rs[2] + rs[3];
        pcnt[blockIdx.x] = rc[0] + rc[1] + rc[2] + rc[3];
    }
}

__global__ void fin2(const float* __restrict__ psum, const float* __restrict__ pcnt,
                     float* __restrict__ out) {
    int t = threadIdx.x;
    float a = t < 32 ? psum[t] : 0.f;
    float c = t < 32 ? pcnt[t] : 0.f;
    #pragma unroll
    for (int off = 32; off; off >>= 1) { a += __shfl_xor(a, off); c += __shfl_xor(c, off); }
    if (t == 0) out[0] = -a / c;
}

extern "C" void kernel_launch(void* const* d_in, const int* in_sizes, int n_in,
                              void* d_out, int out_size, void* d_ws, size_t ws_size,
                              hipStream_t stream) {
    const float* x      = (const float*)d_in[0];
    const int*   labels = (const int*)d_in[1];
    float* out = (float*)d_out;
    char*  ws  = (char*)d_ws;

    unsigned short* xn = (unsigned short*)ws;                  // 2 MB bf16
    float* sd   = (float*)(ws + 2097152);                      // 32 KB
    float* Zp   = (float*)(ws + 2097152 + 32768);              // 512 KB
    float* Sp   = (float*)(ws + 2097152 + 32768 + 524288);     // 512 KB
    float* psum = (float*)(ws + 2097152 + 32768 + 2 * 524288);        // 128 B
    float* pcnt = (float*)(ws + 2097152 + 32768 + 2 * 524288 + 128);  // 128 B

    prep_kernel<<<NN / 4, 256, 0, stream>>>(x, xn, sd);
    cl_main<<<(NN / 64 / 4) * JR, 256, 0, stream>>>(xn, labels, Zp, Sp);
    fin1<<<NN / 256, 256, 0, stream>>>(Zp, Sp, sd, labels, psum, pcnt);
    fin2<<<1, 64, 0, stream>>>(psum, pcnt, out);
}